// Round 2
// baseline (356.711 us; speedup 1.0000x reference)
//
#include <hip/hip_runtime.h>
#include <math.h>

// Problem constants (from reference setup_inputs)
#define B_    8
#define F_    64        // features
#define HW_   65536     // 256*256 pixels
#define NSEG  33        // N_OBJECTS + 1
#define NOBJ  32
#define CHUNK 1024      // pixels per block in segmax kernel
#define CPB   (HW_ / CHUNK)   // 64 chunks per batch
#define FPB   16              // features per block
#define FGRP  (F_ / FPB)      // 4 feature groups
#define ENC_NEG_INF 0x007FFFFFu   // monotonic encoding of -inf

// Monotonic order-preserving float->uint encoding: unsigned max == float max.
__device__ __forceinline__ unsigned enc_f(float x) {
    unsigned u = __float_as_uint(x);
    return u ^ ((unsigned)((int)u >> 31) | 0x80000000u);
}
__device__ __forceinline__ float dec_f(unsigned e) {
    unsigned x = (e & 0x80000000u) ? (e ^ 0x80000000u) : ~e;
    return __uint_as_float(x);
}

// d_ws is poisoned 0xAA before every timed launch -> must re-init every call.
__global__ void init_ws(unsigned* __restrict__ gws) {
    int i = blockIdx.x * blockDim.x + threadIdx.x;
    if (i < B_ * NSEG * F_) gws[i] = ENC_NEG_INF;
}

// One block = (batch, 1024-pixel chunk, 16-feature group). Read-filtered LDS
// max accumulation: ds_read (broadcast-friendly) + compare; atomic only on
// improvement (~8x fewer atomics). Filtered global flush the same way.
__global__ __launch_bounds__(256, 6) void segmax_kernel(
        const float* __restrict__ enc, const int* __restrict__ masks,
        unsigned* __restrict__ gws) {
    __shared__ unsigned acc[FPB * NSEG];   // 2112 B
    const int tid = threadIdx.x;
    const int blk = blockIdx.x;
    const int b     = blk >> 8;            // CPB*FGRP = 256
    const int r     = blk & 255;
    const int chunk = r >> 2;
    const int fg    = r & 3;

    for (int i = tid; i < FPB * NSEG; i += 256) acc[i] = ENC_NEG_INF;

    // Each thread owns 4 consecutive pixels (same pixels for every feature).
    const int4 ids = ((const int4*)(masks + b * HW_ + chunk * CHUNK))[tid];
    __syncthreads();

    const float4* p = (const float4*)(enc + (size_t)b * F_ * HW_
                                      + (size_t)(fg * FPB) * HW_
                                      + chunk * CHUNK) + tid;
    for (int fo = 0; fo < FPB; fo += 8) {
        float4 vbuf[8];
        #pragma unroll
        for (int u = 0; u < 8; ++u)
            vbuf[u] = p[(size_t)(fo + u) * (HW_ / 4)];
        #pragma unroll
        for (int u = 0; u < 8; ++u) {
            unsigned* a = acc + (fo + u) * NSEG;
            unsigned e;
            e = enc_f(vbuf[u].x); if (e > a[ids.x]) atomicMax(a + ids.x, e);
            e = enc_f(vbuf[u].y); if (e > a[ids.y]) atomicMax(a + ids.y, e);
            e = enc_f(vbuf[u].z); if (e > a[ids.z]) atomicMax(a + ids.z, e);
            e = enc_f(vbuf[u].w); if (e > a[ids.w]) atomicMax(a + ids.w, e);
        }
    }
    __syncthreads();

    // Filtered flush to global [b][seg][f] accumulator.
    unsigned* gb = gws + b * (NSEG * F_);
    for (int i = tid; i < FPB * NSEG; i += 256) {
        unsigned val = acc[i];
        if (val != ENC_NEG_INF) {
            int f = i / NSEG + fg * FPB, s = i % NSEG;
            unsigned* cell = gb + s * F_ + f;
            if (val > *cell) atomicMax(cell, val);
        }
    }
}

// One block per batch. Decode vectors, write them out, then the pairwise MLP:
// h[b,i,j,k] = (v_i @ W1[0:64]) + (v_j @ W1[64:128]) + b1 -> sigmoid(h @ W2 + b2)
// connections[b,c,j,i] = out[b,i,j,c]
__global__ __launch_bounds__(256) void mlp_kernel(
        const unsigned* __restrict__ gws,
        const float* __restrict__ W1, const float* __restrict__ b1,
        const float* __restrict__ W2, const float* __restrict__ b2,
        float* __restrict__ out_vec, float* __restrict__ out_conn) {
    const int b = blockIdx.x;
    const int tid = threadIdx.x;
    __shared__ float v[NOBJ * F_];     // [i][f]
    __shared__ float w1s[2 * F_ * 32]; // staged W1 [d][k], 16 KB, k->banks 0..31
    __shared__ float Am[NOBJ * 33];    // A[i][k] + b1[k], stride 33 (bank pad)
    __shared__ float Bm[NOBJ * 33];    // B[j][k]

    // Stage W1 (coalesced float4).
    for (int i = tid; i < 2 * F_ * 32 / 4; i += 256)
        ((float4*)w1s)[i] = ((const float4*)W1)[i];

    // Decode segments 1..32 (segment 0 dropped by reference).
    for (int i = tid; i < NOBJ * F_; i += 256) {
        int s = (i >> 6) + 1, f = i & 63;
        float val = dec_f(gws[b * NSEG * F_ + s * F_ + f]);
        v[i] = val;
        out_vec[b * NOBJ * F_ + i] = val;
    }
    __syncthreads();

    // A[i][k] and B[j][k]: 2048 dots of length 64, all operands in LDS.
    for (int e = tid; e < 2 * NOBJ * 32; e += 256) {
        int half = e >> 10;             // 0 -> A (W1 rows 0..63), 1 -> B (rows 64..127)
        int idx  = e & 1023;
        int i = idx >> 5, k = idx & 31;
        const float* vv = v + i * F_;
        const float* w  = w1s + half * (F_ * 32) + k;   // row stride 32
        float s = 0.f;
        #pragma unroll
        for (int f = 0; f < F_; ++f) s = fmaf(vv[f], w[f * 32], s);
        if (half) Bm[i * 33 + k] = s;
        else      Am[i * 33 + k] = s + b1[k];
    }
    __syncthreads();

    // 1024 (i,j) pairs -> 4 sigmoid outputs each.
    for (int e = tid; e < NOBJ * NOBJ; e += 256) {
        int i = e >> 5, j = e & 31;
        float o0 = b2[0], o1 = b2[1], o2 = b2[2], o3 = b2[3];
        #pragma unroll
        for (int k = 0; k < 32; ++k) {
            float h = Am[i * 33 + k] + Bm[j * 33 + k];
            o0 = fmaf(h, W2[k * 4 + 0], o0);
            o1 = fmaf(h, W2[k * 4 + 1], o1);
            o2 = fmaf(h, W2[k * 4 + 2], o2);
            o3 = fmaf(h, W2[k * 4 + 3], o3);
        }
        float* oc = out_conn + (size_t)b * 4 * NOBJ * NOBJ + j * NOBJ + i;
        oc[0 * NOBJ * NOBJ] = 1.f / (1.f + expf(-o0));
        oc[1 * NOBJ * NOBJ] = 1.f / (1.f + expf(-o1));
        oc[2 * NOBJ * NOBJ] = 1.f / (1.f + expf(-o2));
        oc[3 * NOBJ * NOBJ] = 1.f / (1.f + expf(-o3));
    }
}

extern "C" void kernel_launch(void* const* d_in, const int* in_sizes, int n_in,
                              void* d_out, int out_size, void* d_ws, size_t ws_size,
                              hipStream_t stream) {
    const float* enc   = (const float*)d_in[0];
    const int*   masks = (const int*)  d_in[1];
    const float* W1    = (const float*)d_in[2];
    const float* b1    = (const float*)d_in[3];
    const float* W2    = (const float*)d_in[4];
    const float* b2    = (const float*)d_in[5];

    float* out_vec  = (float*)d_out;                 // 8*32*64 = 16384 floats
    float* out_conn = out_vec + B_ * NOBJ * F_;      // 8*4*32*32 = 32768 floats
    unsigned* gws   = (unsigned*)d_ws;               // 8*33*64 uints = 67.6 KB

    const int n = B_ * NSEG * F_;
    init_ws<<<(n + 255) / 256, 256, 0, stream>>>(gws);
    segmax_kernel<<<B_ * CPB * FGRP, 256, 0, stream>>>(enc, masks, gws);
    mlp_kernel<<<B_, 256, 0, stream>>>(gws, W1, b1, W2, b2, out_vec, out_conn);
}

// Round 3
// 208.682 us; speedup vs baseline: 1.7094x; 1.7094x over previous
//
#include <hip/hip_runtime.h>
#include <math.h>

// Problem constants (from reference setup_inputs)
#define B_      8
#define F_      64        // features
#define HW_     65536     // 256*256 pixels
#define NSEG    33        // N_OBJECTS + 1
#define NOBJ    32
#define FPB     8         // features per segmax block
#define SLICES  8         // pixel slices per batch
#define PIXB    (HW_ / SLICES)   // 8192 pixels per block
// d_ws layout: float part[b][slice][NSEG][F_]  = 8*8*33*64 floats = 540,672 B.
// Every slot is written unconditionally by exactly one block -> no init pass,
// no atomics, poisoned ws is harmless.

// segmax: grid = 8 b * 8 fgroup * 8 slice = 512 blocks, 256 threads.
// Per-thread-PRIVATE LDS accumulators acc[f_local][seg][lane]: address word
// index = f*1056 + seg*32 + lane  -> bank = lane mod 32 for ANY seg: zero
// bank conflicts, zero atomic contention by construction. Same-wave DS ops
// retire in order, so read-max-write on repeated ids is safe.
__global__ __launch_bounds__(256) void segmax_kernel(
        const float* __restrict__ enc, const int* __restrict__ masks,
        float* __restrict__ part) {
    __shared__ float acc[FPB * NSEG * 32];   // 33,792 B
    const int tid = threadIdx.x;
    const int blk = blockIdx.x;
    const int b     = blk >> 6;
    const int fg    = (blk >> 3) & 7;
    const int slice = blk & 7;

    for (int i = tid; i < FPB * NSEG * 32; i += 256) acc[i] = -INFINITY;
    __syncthreads();

    const int fl = tid >> 5;      // feature within group: 0..7
    const int l  = tid & 31;      // private lane slot
    float* a = acc + fl * (NSEG * 32) + l;   // + id*32 per element

    const float4* ep = (const float4*)(enc + ((size_t)(b * F_ + fg * FPB + fl)) * HW_
                                       + slice * PIXB) + l;
    const int4*   mp = (const int4*)(masks + (size_t)b * HW_ + slice * PIXB) + l;

    #pragma unroll 8
    for (int c = 0; c < PIXB / 128; ++c) {     // 64 iters, 128 pixels each
        float4 v  = ep[c * 32];
        int4   id = mp[c * 32];
        float o;
        o = a[id.x * 32]; a[id.x * 32] = fmaxf(o, v.x);
        o = a[id.y * 32]; a[id.y * 32] = fmaxf(o, v.y);
        o = a[id.z * 32]; a[id.z * 32] = fmaxf(o, v.z);
        o = a[id.w * 32]; a[id.w * 32] = fmaxf(o, v.w);
    }
    __syncthreads();

    // Reduce 32 lane-copies per (f_local, seg); write per-slice partial max.
    float* dst = part + (((size_t)b * SLICES + slice) * NSEG) * F_;
    for (int cell = tid; cell < FPB * NSEG; cell += 256) {
        int f = cell & 7, s = cell >> 3;
        const float* row = acc + f * (NSEG * 32) + s * 32;
        float m = -INFINITY;
        #pragma unroll
        for (int k = 0; k < 32; k += 4) {
            float4 q = *(const float4*)(row + k);
            m = fmaxf(m, fmaxf(fmaxf(q.x, q.y), fmaxf(q.z, q.w)));
        }
        dst[s * F_ + fg * FPB + f] = m;
    }
}

// mlp: grid = 8 b * 4 i-tiles = 32 blocks. Reduces the 8 slice partials,
// writes vectors, then h = A_i + B_j + b1, out = sigmoid(h@W2 + b2),
// connections[b][c][j][i] = out[i][j][c]. All weights staged in LDS.
__global__ __launch_bounds__(256) void mlp_kernel(
        const float* __restrict__ part,
        const float* __restrict__ W1, const float* __restrict__ b1,
        const float* __restrict__ W2, const float* __restrict__ b2,
        float* __restrict__ out_vec, float* __restrict__ out_conn) {
    const int b   = blockIdx.x >> 2;
    const int it  = blockIdx.x & 3;          // i-tile: i = it*8 .. it*8+7
    const int tid = threadIdx.x;
    __shared__ float v[NOBJ * 65];           // [obj][f], pad 65 kills i-aliasing
    __shared__ float w1s[2 * F_ * 32];       // [d][k], 16 KB
    __shared__ float w2s[32 * 4];
    __shared__ float b1s[32];
    __shared__ float Am[8 * 36];             // [i_loc][k], pad 36 (f4-aligned)
    __shared__ float Bm[NOBJ * 36];

    for (int i = tid; i < 2 * F_ * 32 / 4; i += 256)
        ((float4*)w1s)[i] = ((const float4*)W1)[i];
    if (tid < 32) { w2s[tid*4+0]=W2[tid*4+0]; w2s[tid*4+1]=W2[tid*4+1];
                    w2s[tid*4+2]=W2[tid*4+2]; w2s[tid*4+3]=W2[tid*4+3];
                    b1s[tid] = b1[tid]; }

    // Slice-reduce: cells (s,f) for s=1..32, f=0..63. Coalesced over f.
    for (int cell = tid; cell < NOBJ * F_; cell += 256) {
        int s = (cell >> 6) + 1, f = cell & 63;
        float m = -INFINITY;
        #pragma unroll
        for (int sl = 0; sl < SLICES; ++sl)
            m = fmaxf(m, part[(((size_t)b * SLICES + sl) * NSEG + s) * F_ + f]);
        v[(s - 1) * 65 + f] = m;
        if (it == 0) out_vec[b * NOBJ * F_ + cell] = m;
    }
    __syncthreads();

    // 1280 length-64 dots as 320 float4-dots: d<64 -> Am (8 i_loc x 8 kg),
    // d>=64 -> Bm (32 j x 8 kg). Broadcast-friendly LDS access.
    for (int d = tid; d < 320; d += 256) {
        int kg, obj, half;
        if (d < 64) { half = 0; obj = it * 8 + (d >> 3); kg = d & 7; }
        else        { half = 1; obj = (d - 64) >> 3;     kg = d & 7; }
        const float* vv = v + obj * 65;
        const float* w  = w1s + half * (F_ * 32) + kg * 4;
        float4 s4 = {0.f, 0.f, 0.f, 0.f};
        #pragma unroll
        for (int f = 0; f < F_; ++f) {
            float4 wf = *(const float4*)(w + f * 32);
            float x = vv[f];
            s4.x = fmaf(x, wf.x, s4.x); s4.y = fmaf(x, wf.y, s4.y);
            s4.z = fmaf(x, wf.z, s4.z); s4.w = fmaf(x, wf.w, s4.w);
        }
        if (half == 0) {
            float4 bb = *(const float4*)(b1s + kg * 4);
            s4.x += bb.x; s4.y += bb.y; s4.z += bb.z; s4.w += bb.w;
            *(float4*)(Am + (d >> 3) * 36 + kg * 4) = s4;
        } else {
            *(float4*)(Bm + obj * 36 + kg * 4) = s4;
        }
    }
    __syncthreads();

    // 256 (i,j) pairs: one per thread.
    {
        int i_loc = tid >> 5, j = tid & 31;
        float o0 = b2[0], o1 = b2[1], o2 = b2[2], o3 = b2[3];
        #pragma unroll
        for (int kg = 0; kg < 8; ++kg) {
            float4 ha = *(const float4*)(Am + i_loc * 36 + kg * 4);
            float4 hb = *(const float4*)(Bm + j * 36 + kg * 4);
            float h0 = ha.x + hb.x, h1 = ha.y + hb.y;
            float h2 = ha.z + hb.z, h3 = ha.w + hb.w;
            const float* w2 = w2s + kg * 16;
            o0 = fmaf(h0, w2[0],  fmaf(h1, w2[4],  fmaf(h2, w2[8],  fmaf(h3, w2[12], o0))));
            o1 = fmaf(h0, w2[1],  fmaf(h1, w2[5],  fmaf(h2, w2[9],  fmaf(h3, w2[13], o1))));
            o2 = fmaf(h0, w2[2],  fmaf(h1, w2[6],  fmaf(h2, w2[10], fmaf(h3, w2[14], o2))));
            o3 = fmaf(h0, w2[3],  fmaf(h1, w2[7],  fmaf(h2, w2[11], fmaf(h3, w2[15], o3))));
        }
        float* oc = out_conn + (size_t)b * 4 * NOBJ * NOBJ + j * NOBJ + (it * 8 + i_loc);
        oc[0 * NOBJ * NOBJ] = 1.f / (1.f + expf(-o0));
        oc[1 * NOBJ * NOBJ] = 1.f / (1.f + expf(-o1));
        oc[2 * NOBJ * NOBJ] = 1.f / (1.f + expf(-o2));
        oc[3 * NOBJ * NOBJ] = 1.f / (1.f + expf(-o3));
    }
}

extern "C" void kernel_launch(void* const* d_in, const int* in_sizes, int n_in,
                              void* d_out, int out_size, void* d_ws, size_t ws_size,
                              hipStream_t stream) {
    const float* enc   = (const float*)d_in[0];
    const int*   masks = (const int*)  d_in[1];
    const float* W1    = (const float*)d_in[2];
    const float* b1    = (const float*)d_in[3];
    const float* W2    = (const float*)d_in[4];
    const float* b2    = (const float*)d_in[5];

    float* out_vec  = (float*)d_out;                 // 8*32*64 = 16384 floats
    float* out_conn = out_vec + B_ * NOBJ * F_;      // 8*4*32*32 = 32768 floats
    float* part     = (float*)d_ws;                  // 540,672 B slice partials

    segmax_kernel<<<B_ * SLICES * (F_ / FPB), 256, 0, stream>>>(enc, masks, part);
    mlp_kernel<<<B_ * 4, 256, 0, stream>>>(part, W1, b1, W2, b2, out_vec, out_conn);
}